// Round 16
// baseline (316.461 us; speedup 1.0000x reference)
//
#include <hip/hip_runtime.h>
#include <stdint.h>

#define Mdim 8192
#define Ndim 4096
#define Kdim 4096

#define BM 256
#define BN 256
#define BK 64
#define NT2 (Kdim / BK)   // 64 K-tiles

typedef float f32x4 __attribute__((ext_vector_type(4)));
typedef __bf16 bf16x8 __attribute__((ext_vector_type(8)));
typedef unsigned short ushort_t;

#define FMAXC 3.3858093490333422e+38f  // FLT_MAX * (1 - 0.005)

__device__ __forceinline__ ushort_t f2bf(float f) {
    unsigned u = __float_as_uint(f);
    u += 0x7fffu + ((u >> 16) & 1u);   // round-to-nearest-even
    return (ushort_t)(u >> 16);
}

__device__ __forceinline__ void gload_lds16(const void* g, void* l) {
    __builtin_amdgcn_global_load_lds(
        (const __attribute__((address_space(1))) uint32_t*)g,
        (__attribute__((address_space(3))) uint32_t*)(uint32_t)(uintptr_t)l,
        16, 0, 0);
}

#define SGB(mask, n) __builtin_amdgcn_sched_group_barrier(mask, n, 0)

// ---------------------------------------------------------------------------
// Kernel 1: dequant + CSR outliers -> bf16 weight row (row-major, verified).
// ---------------------------------------------------------------------------
__global__ __launch_bounds__(128) void dequant_kernel(
        const int* __restrict__ qw, const float* __restrict__ lut,
        const int* __restrict__ rows, const int* __restrict__ cols,
        const float* __restrict__ vals, ushort_t* __restrict__ w16) {
    __shared__ float wrow[128 * 33];
    __shared__ float slut[16];
    const int o = blockIdx.x;
    const int t = threadIdx.x;

    if (t < 16) slut[t] = lut[o * 16 + t];
    __syncthreads();

    const int q0 = qw[0 * Ndim * 128 + o * 128 + t];
    const int q1 = qw[1 * Ndim * 128 + o * 128 + t];
    const int q2 = qw[2 * Ndim * 128 + o * 128 + t];
    const int q3 = qw[3 * Ndim * 128 + o * 128 + t];
    float* dst = &wrow[t * 33];
#pragma unroll
    for (int j = 0; j < 32; ++j) {
        int idx = (((q0 >> j) & 1) << 3) | (((q1 >> j) & 1) << 2) |
                  (((q2 >> j) & 1) << 1) | ((q3 >> j) & 1);
        dst[j] = slut[idx];
    }
    __syncthreads();

    const int beg = rows[o], end = rows[o + 1];
    for (int k = beg + t; k < end; k += 128) {
        int c = cols[k];
        atomicAdd(&wrow[c + (c >> 5)], vals[k]);
    }
    __syncthreads();

    __align__(16) ushort_t tmp[32];
#pragma unroll
    for (int j = 0; j < 32; ++j) tmp[j] = f2bf(dst[j]);
    uint4* dstg = (uint4*)(w16 + (size_t)o * Kdim + t * 32);
    const uint4* srcg = (const uint4*)tmp;
#pragma unroll
    for (int j = 0; j < 4; ++j) dstg[j] = srcg[j];
}

// ---------------------------------------------------------------------------
// Kernel 2: x f32 -> bf16, FRAGMENT-PACKED for direct global->reg A loads.
// 16B unit u = frag*64 + lane; frag = mblk*128 + kt2 (kt2 = k/32);
// m = mblk*16 + (lane&15); k = kt2*32 + (lane>>4)*8.
// Reads: per wave 16 rows x 128B contiguous (full-line coalesced).
// Writes: consecutive 16B per thread (perfect). No amplification.
// ---------------------------------------------------------------------------
__global__ __launch_bounds__(256) void convx_kernel(
        const float* __restrict__ x, ushort_t* __restrict__ y) {
    size_t u = (size_t)blockIdx.x * 256 + threadIdx.x;
    const int lane = (int)(u & 63);
    const size_t frag = u >> 6;
    const int kt2 = (int)(frag & 127);
    const size_t mblk = frag >> 7;
    const size_t m = mblk * 16 + (lane & 15);
    const size_t k = (size_t)kt2 * 32 + (lane >> 4) * 8;
    const float* src = x + m * Kdim + k;
    float4 a = *(const float4*)(src);
    float4 b = *(const float4*)(src + 4);
    __align__(16) ushort_t r[8] = {f2bf(a.x), f2bf(a.y), f2bf(a.z), f2bf(a.w),
                                   f2bf(b.x), f2bf(b.y), f2bf(b.z), f2bf(b.w)};
    *(uint4*)(y + u * 8) = *(const uint4*)r;
}

// ---------------------------------------------------------------------------
// Kernel 3: bf16 GEMM, 256x256, BK=64.  Three-pipe operand split:
//   A: fragment-packed GLOBAL->REGISTER (1 coalesced dwordx4 = 1 fragment),
//      register-dbuf one k-step ahead; compiler's per-register counted vmcnt
//      handles A waits.  A panels L2-resident (bn-fastest XCD swizzle).
//   B: R9's verified LDS path (dbuf 2x32KB, zero-conflict swizzle, 4
//      gload_lds per thread per tile).
//   LDS/tile drops 240KB -> 96KB; MFMA (2368cyc) || VMEM-L2 (~2200) ||
//   LDS (~1000) on separate pipes.
// Manual wait: vmcnt(8) once per tile (FIFO [B-stage:4, A-loads:8] -> retires
// B(t+1); in practice the compiler's A-waits retire it earlier). Never 0.
// WAR (B dbuf): stage(t+1) targets the buffer read during t-1, whose reads
// retired before the end-of-(t-1) barrier. One barrier per tile.
// ---------------------------------------------------------------------------
__global__ __launch_bounds__(512, 2) void gemm_kernel(
        const ushort_t* __restrict__ A, const ushort_t* __restrict__ Bw,
        const float* __restrict__ bias, float* __restrict__ C) {
    __shared__ __align__(16) char lds[65536];   // B dbuf only

    // XCD swizzle, bn-fastest: 32 concurrent blocks per XCD share bm pair
    // (A panels 2x2MB -> L2-resident), B via L3. nwg=512 (%8==0).
    const int wgid = blockIdx.x;
    const int swz = (wgid & 7) * 64 + (wgid >> 3);
    const int bn = swz & 15, bm = swz >> 4;
    const int m0 = bm * BM, n0 = bn * BN;

    const int tid = threadIdx.x;
    const int lane = tid & 63, wid = tid >> 6;
    const int wr = wid >> 2, wc = wid & 3;       // 2M x 4N wave grid
    const int fr = lane & 15, kg = lane >> 4;

    // ---- A fragment-packed base: frag = mblk*128 + kt2, mblk0 = (bm*2+wr)*8
    const uint4* pA0 = (const uint4*)A + ((size_t)((bm * 2 + wr) * 8) * 128) * 64 + lane;

    // ---- B staging geometry (inverse-swizzled source, linear LDS dest) [R9]
    const int srow = tid >> 3;
    const int scol = (((tid & 7) ^ (srow & 7)) * 8);
    const ushort_t* gB = Bw + (size_t)(n0 + srow) * Kdim + scol;

    // ---- B ds_read swizzled offsets per k-step (row stride 128 B) [R9]
    const int offB0 = fr * 128 + (((kg) ^ (fr & 7)) << 4);
    const int offB1 = fr * 128 + (((4 | kg) ^ (fr & 7)) << 4);

    f32x4 acc[8][4];
#pragma unroll
    for (int i = 0; i < 8; ++i)
#pragma unroll
        for (int j = 0; j < 4; ++j) acc[i][j] = (f32x4){0.f, 0.f, 0.f, 0.f};

    auto stageB = [&](int buf, int t1) {
        const ushort_t* sb = gB + (size_t)t1 * BK;
        char* db = lds + buf * 32768 + tid * 16;
#pragma unroll
        for (int j = 0; j < 4; ++j)
            gload_lds16(sb + (size_t)j * 64 * Kdim, db + j * 8192);
    };
    auto loadA = [&](bf16x8 (&F)[8], int kt2) {
#pragma unroll
        for (int mf = 0; mf < 8; ++mf)
            F[mf] = *(const bf16x8*)(pA0 + (size_t)mf * 8192 + kt2 * 64);
    };
    auto readB = [&](bf16x8 (&F)[4], int buf, int off) {
#pragma unroll
        for (int nf = 0; nf < 4; ++nf)
            F[nf] = *(const bf16x8*)(lds + buf * 32768 + wc * 8192 + nf * 2048 + off);
    };
    auto mfma32 = [&](bf16x8 (&FA)[8], bf16x8 (&FB)[4]) {
        __builtin_amdgcn_s_setprio(1);
#pragma unroll
        for (int m = 0; m < 8; ++m)
#pragma unroll
            for (int n = 0; n < 4; ++n)
                acc[m][n] = __builtin_amdgcn_mfma_f32_16x16x32_bf16(
                    FA[m], FB[n], acc[m][n], 0, 0, 0);
        __builtin_amdgcn_s_setprio(0);
    };

    bf16x8 Aa[8], Ab[8], FB[4];

    // ---- prologue: stage B(0); load A(0,s0); wait B(0) (FIFO [B:4, A:8])
    stageB(0, 0);
    loadA(Aa, 0);
    asm volatile("s_waitcnt vmcnt(8)");
    __builtin_amdgcn_sched_barrier(0);
    __builtin_amdgcn_s_barrier();

    // ===== main loop: tiles 0..62 (each stages B(t+1)) =====
#pragma unroll 1
    for (int t = 0; t < NT2 - 1; ++t) {
        const int bufc = t & 1, bufn = (t + 1) & 1;

        // --- s0: MFMA(Aa x B ks0); issue B-stage(t+1) + A(t,s1)
        stageB(bufn, t + 1);
        loadA(Ab, t * 2 + 1);
        readB(FB, bufc, offB0);
        SGB(0x30, 12); SGB(0x100, 4); SGB(0x8, 32);
        mfma32(Aa, FB);

        // --- s1: MFMA(Ab x B ks1); issue A(t+1,s0)
        loadA(Aa, (t + 1) * 2);
        readB(FB, bufc, offB1);
        SGB(0x30, 8); SGB(0x100, 4); SGB(0x8, 32);
        mfma32(Ab, FB);

        asm volatile("s_waitcnt vmcnt(8)");   // B(t+1) retired (FIFO safety)
        __builtin_amdgcn_sched_barrier(0);
        __builtin_amdgcn_s_barrier();
    }

    // ===== tail: tile 63 (buf 1, no staging, no barrier) =====
    {
        loadA(Ab, 127);
        readB(FB, 1, offB0);
        mfma32(Aa, FB);
        readB(FB, 1, offB1);
        mfma32(Ab, FB);
    }

    // ---- epilogue: C/D layout col = lane&15, row = (lane>>4)*4 + reg
    const int rg = lane >> 4;
#pragma unroll
    for (int nf = 0; nf < 4; ++nf) {
        const int col = n0 + wc * 64 + nf * 16 + fr;
        const float bv = bias[col];
#pragma unroll
        for (int mf = 0; mf < 8; ++mf) {
            const int row = m0 + wr * 128 + mf * 16 + rg * 4;
            float* outp = C + (size_t)row * Ndim + col;
#pragma unroll
            for (int j = 0; j < 4; ++j) {
                float v = acc[mf][nf][j] + bv;
                v = fminf(fmaxf(v, -FMAXC), FMAXC);
                outp[(size_t)j * Ndim] = v;
            }
        }
    }
}

extern "C" void kernel_launch(void* const* d_in, const int* in_sizes, int n_in,
                              void* d_out, int out_size, void* d_ws, size_t ws_size,
                              hipStream_t stream) {
    const float* x    = (const float*)d_in[0];
    const int*   qw   = (const int*)d_in[1];
    const float* lut  = (const float*)d_in[2];
    const int*   rows = (const int*)d_in[3];
    const int*   cols = (const int*)d_in[4];
    const float* vals = (const float*)d_in[5];
    const float* bias = (const float*)d_in[6];
    float* out = (float*)d_out;

    ushort_t* x16 = (ushort_t*)d_ws;                       // 64 MiB (frag-packed)
    ushort_t* w16 = x16 + (size_t)Mdim * Kdim;             // 32 MiB (row-major)

    hipLaunchKernelGGL(dequant_kernel, dim3(Ndim), dim3(128), 0, stream,
                       qw, lut, rows, cols, vals, w16);
    hipLaunchKernelGGL(convx_kernel, dim3((Mdim * Kdim) / (256 * 8)), dim3(256), 0, stream,
                       x, x16);
    hipLaunchKernelGGL(gemm_kernel, dim3((Mdim / BM) * (Ndim / BN)), dim3(512), 0, stream,
                       x16, w16, bias, out);
}